// Round 14
// baseline (1089.231 us; speedup 1.0000x reference)
//
#include <hip/hip_runtime.h>
#include <hip/hip_bf16.h>

// AUGRU (DIEN) fused recurrent kernel. fp32 I/O, bf16 MFMA compute.
// B=2048, T=200, D=H=128. Round 17: TLP via BM=4 (512 blocks, 2 blocks/CU,
// 2 waves/SIMD). The R8 template (measured 267-272us, reproducible) is
// unchanged in all mappings/barriers; only BM, grid, pad-row guards, and
// __launch_bounds__(256,2). Pad rows 4-7: sl=0 -> h stays 0 -> hb/rh stay 0
// (correct GEMM padding); OUT stores guarded. Mechanism: two independent
// blocks per CU interleave so one block's barrier/latency stalls (~28% of
// step) hide under the other's compute.

#define BB   2048
#define TT   200
#define DD   128
#define HH   128
#define NG   256
#define BM   4       // batch rows per block (rows 4..15 of tiles = zero pad)
#define SB   136     // bf16 tile row stride (shorts): 68 dwords = 4 mod 32
#define NTH  256

typedef __attribute__((ext_vector_type(8))) __bf16 bf16x8;
typedef __attribute__((ext_vector_type(4))) float  f32x4;

#define MFMA(a, b, c) __builtin_amdgcn_mfma_f32_16x16x32_bf16((a), (b), (c), 0, 0, 0)

union bfu { __bf16 b; unsigned short u; };
__device__ __forceinline__ unsigned short f2bf(float f) { bfu c; c.b = (__bf16)f; return c.u; }
__device__ __forceinline__ __bf16 f2bfv(float f) { return (__bf16)f; }
__device__ __forceinline__ float sigm(float x) { return __builtin_amdgcn_rcpf(1.0f + __expf(-x)); }

// Barrier with LDS-ordering only (no vmcnt drain; x-prefetch + OUT stores
// stay in flight across steps). Cross-wave ordering here is LDS-only.
__device__ __forceinline__ void lds_barrier() {
    __builtin_amdgcn_sched_barrier(0);
    asm volatile("s_waitcnt lgkmcnt(0)" ::: "memory");
    __builtin_amdgcn_s_barrier();
    __builtin_amdgcn_sched_barrier(0);
}

__global__ __launch_bounds__(NTH, 2)
void augru_kernel(const float* __restrict__ X,    // [B,T,D]
                  const float* __restrict__ ATT,  // [B,T]
                  const int*   __restrict__ SL,   // [B]
                  const float* __restrict__ WG,   // [256,256]
                  const float* __restrict__ BG,   // [256]
                  const float* __restrict__ WC,   // [256,128]
                  const float* __restrict__ BC,   // [128]
                  float*       __restrict__ OUT)  // [B,T,H]
{
    __shared__ unsigned short xb[2][16 * SB];  // x_t double buffer, bf16, rows BM..15 = 0
    __shared__ unsigned short hb[16 * SB];     // h bf16 (A-frag source), rows BM..15 = 0
    __shared__ unsigned short rh[16 * SB];     // r*h bf16, rows BM..15 = 0
    __shared__ float attall[BM * TT];
    __shared__ int   slbuf[8];                 // rows >= BM: 0 (pad)

    const int tid  = threadIdx.x;
    const int wave = tid >> 6;       // 0..3
    const int lane = tid & 63;
    const int quad = lane >> 4;
    const int l16  = lane & 15;
    const int b0   = blockIdx.x * BM;
    const int qq   = quad & 1;       // row-group select after redistribution
    const int top  = quad >> 1;
    const int r0   = 4 * qq + 2 * top;   // this lane handles rows r0, r0+1 (may be pad)
    const bool realr = (r0 < BM);        // rows r0, r0+1 are real batch rows

    // ---------------- one-time init ----------------
    for (int i = tid; i < 2 * 16 * SB; i += NTH) xb[0][i] = 0;   // both buffers
    for (int i = tid; i < 16 * SB; i += NTH) hb[i] = 0;
    for (int i = tid; i < 16 * SB; i += NTH) rh[i] = 0;
    for (int i = tid; i < BM * TT; i += NTH) attall[i] = ATT[(long)b0 * TT + i];
    if (tid < 8) slbuf[tid] = (tid < BM) ? SL[b0 + tid] : 0;

    // Columns this thread owns (cand / r-gate / h / out): c0, c1 = c0+16.
    // u-gate cols: c0+128, c1+128.
    const int c0 = wave * 32 + l16;
    const int c1 = c0 + 16;
    const float bgr0 = BG[c0],      bgr1 = BG[c1];        // r-gate biases
    const float bgu0 = BG[c0 + HH], bgu1 = BG[c1 + HH];   // u-gate biases
    const float bc0v = BC[c0],      bc1v = BC[c1];        // cand biases

    // Weight B-fragments (bf16) in registers.
    // B-frag (16x16x32): lane holds B[k = kk*32 + quad*8 + j][col]
    bf16x8 bgf[4][8], bcf[2][8];
    {
        #pragma unroll
        for (int kk = 0; kk < 8; ++kk) {
            bf16x8 t0, t1, t2, t3, t4, t5;
            #pragma unroll
            for (int j = 0; j < 8; ++j) {
                const int k = kk * 32 + quad * 8 + j;
                t0[j] = f2bfv(WG[k * NG + c0]);
                t1[j] = f2bfv(WG[k * NG + c1]);
                t2[j] = f2bfv(WG[k * NG + c0 + HH]);
                t3[j] = f2bfv(WG[k * NG + c1 + HH]);
                t4[j] = f2bfv(WC[k * HH + c0]);
                t5[j] = f2bfv(WC[k * HH + c1]);
            }
            bgf[0][kk] = t0; bgf[1][kk] = t1; bgf[2][kk] = t2; bgf[3][kk] = t3;
            bcf[0][kk] = t4; bcf[1][kk] = t5;
        }
    }
    __syncthreads();   // full barrier once (init loads must land)

    int tmax = 0;
    #pragma unroll
    for (int r = 0; r < 8; ++r) tmax = max(tmax, slbuf[r]);
    const int sl0 = slbuf[r0], sl1 = slbuf[r0 + 1];   // pad rows: 0 -> never valid

    // Persistent per-thread state: h (fp32) for (rows r0,r0+1) x (cols c0,c1).
    float h00 = 0.f, h01 = 0.f, h10 = 0.f, h11 = 0.f;   // hXY: X=row, Y=col

    const int srow = tid >> 5;   // 0..7 (rows >= BM: no staging, xb pad rows stay 0)
    const int sseg = tid & 31;
    const bool stg = (srow < BM);

    // prologue: stage x(0), prefetch x(1)
    float4 xpre;
    if (stg && tmax > 0) {
        xpre = *(const float4*)&X[((long)(b0 + srow) * TT + 0) * DD + sseg * 4];
        ushort4 v; v.x = f2bf(xpre.x); v.y = f2bf(xpre.y); v.z = f2bf(xpre.z); v.w = f2bf(xpre.w);
        *(ushort4*)&xb[0][srow * SB + sseg * 4] = v;
        if (tmax > 1)
            xpre = *(const float4*)&X[((long)(b0 + srow) * TT + 1) * DD + sseg * 4];
    }
    lds_barrier();   // SYNC A for t=0 (x(1) prefetch stays in flight)

    // ---------------- time loop ----------------
    for (int t = 0; t < tmax; ++t) {
        const unsigned short* xc = &xb[t & 1][0];

        // x A-fragments: loaded once, reused by both GEMMs this step.
        bf16x8 afx[4];
        #pragma unroll
        for (int kk = 0; kk < 4; ++kk)
            afx[kk] = *(const bf16x8*)&xc[l16 * SB + kk * 32 + quad * 8];

        // attention scores for this step (pad rows: value irrelevant, h frozen)
        const float at0 = realr ? attall[r0 * TT + t] : 0.f;
        const float at1 = realr ? attall[(r0 + 1) * TT + t] : 0.f;

        // ---- gate GEMM: [x|h] @ Wg, 8 independent MFMA chains ----
        f32x4 a0 = {0.f,0.f,0.f,0.f}, a1 = {0.f,0.f,0.f,0.f};
        f32x4 a2 = {0.f,0.f,0.f,0.f}, a3 = {0.f,0.f,0.f,0.f};
        f32x4 a4 = {0.f,0.f,0.f,0.f}, a5 = {0.f,0.f,0.f,0.f};
        f32x4 a6 = {0.f,0.f,0.f,0.f}, a7 = {0.f,0.f,0.f,0.f};
        // x part (kk = 0..3)
        a0 = MFMA(afx[0], bgf[0][0], a0); a2 = MFMA(afx[0], bgf[1][0], a2);
        a4 = MFMA(afx[0], bgf[2][0], a4); a6 = MFMA(afx[0], bgf[3][0], a6);
        a1 = MFMA(afx[1], bgf[0][1], a1); a3 = MFMA(afx[1], bgf[1][1], a3);
        a5 = MFMA(afx[1], bgf[2][1], a5); a7 = MFMA(afx[1], bgf[3][1], a7);
        a0 = MFMA(afx[2], bgf[0][2], a0); a2 = MFMA(afx[2], bgf[1][2], a2);
        a4 = MFMA(afx[2], bgf[2][2], a4); a6 = MFMA(afx[2], bgf[3][2], a6);
        a1 = MFMA(afx[3], bgf[0][3], a1); a3 = MFMA(afx[3], bgf[1][3], a3);
        a5 = MFMA(afx[3], bgf[2][3], a5); a7 = MFMA(afx[3], bgf[3][3], a7);
        // h part (kk = 4..7)
        {
            const bf16x8 afh0 = *(const bf16x8*)&hb[l16 * SB + 0 * 32 + quad * 8];
            const bf16x8 afh1 = *(const bf16x8*)&hb[l16 * SB + 1 * 32 + quad * 8];
            const bf16x8 afh2 = *(const bf16x8*)&hb[l16 * SB + 2 * 32 + quad * 8];
            const bf16x8 afh3 = *(const bf16x8*)&hb[l16 * SB + 3 * 32 + quad * 8];
            a0 = MFMA(afh0, bgf[0][4], a0); a2 = MFMA(afh0, bgf[1][4], a2);
            a4 = MFMA(afh0, bgf[2][4], a4); a6 = MFMA(afh0, bgf[3][4], a6);
            a1 = MFMA(afh1, bgf[0][5], a1); a3 = MFMA(afh1, bgf[1][5], a3);
            a5 = MFMA(afh1, bgf[2][5], a5); a7 = MFMA(afh1, bgf[3][5], a7);
            a0 = MFMA(afh2, bgf[0][6], a0); a2 = MFMA(afh2, bgf[1][6], a2);
            a4 = MFMA(afh2, bgf[2][6], a4); a6 = MFMA(afh2, bgf[3][6], a6);
            a1 = MFMA(afh3, bgf[0][7], a1); a3 = MFMA(afh3, bgf[1][7], a3);
            a5 = MFMA(afh3, bgf[2][7], a5); a7 = MFMA(afh3, bgf[3][7], a7);
        }

        // stage x(t+1) into the other buffer; then prefetch x(t+2)
        if (stg && t + 1 < tmax) {
            ushort4 v; v.x = f2bf(xpre.x); v.y = f2bf(xpre.y); v.z = f2bf(xpre.z); v.w = f2bf(xpre.w);
            *(ushort4*)&xb[(t + 1) & 1][srow * SB + sseg * 4] = v;
            if (t + 2 < tmax)
                xpre = *(const float4*)&X[((long)(b0 + srow) * TT + (t + 2)) * DD + sseg * 4];
        }

        // ---- gate epilogue (full-lane via xor-32 redistribution) ----
        const f32x4 gr0 = a0 + a1;   // r-gate, col c0
        const f32x4 gr1 = a2 + a3;   // r-gate, col c1
        const f32x4 gu0 = a4 + a5;   // u-gate, col c0+128
        const f32x4 gu1 = a6 + a7;   // u-gate, col c1+128
        const float r02 = __shfl_xor(gr0[2], 32, 64), r03 = __shfl_xor(gr0[3], 32, 64);
        const float r12 = __shfl_xor(gr1[2], 32, 64), r13 = __shfl_xor(gr1[3], 32, 64);
        const float u02 = __shfl_xor(gu0[2], 32, 64), u03 = __shfl_xor(gu0[3], 32, 64);
        const float u12 = __shfl_xor(gu1[2], 32, 64), u13 = __shfl_xor(gu1[3], 32, 64);
        float ug00, ug01, ug10, ug11;   // att * sigmoid(u), [row][col]
        {
            // col c0
            const float rs00 = sigm((top ? r02 : gr0[0]) + bgr0);   // row r0
            const float rs10 = sigm((top ? r03 : gr0[1]) + bgr0);   // row r0+1
            rh[r0 * SB + c0]       = f2bf(rs00 * h00);
            rh[(r0 + 1) * SB + c0] = f2bf(rs10 * h10);
            ug00 = at0 * sigm((top ? u02 : gu0[0]) + bgu0);
            ug10 = at1 * sigm((top ? u03 : gu0[1]) + bgu0);
            // col c1
            const float rs01 = sigm((top ? r12 : gr1[0]) + bgr1);
            const float rs11 = sigm((top ? r13 : gr1[1]) + bgr1);
            rh[r0 * SB + c1]       = f2bf(rs01 * h01);
            rh[(r0 + 1) * SB + c1] = f2bf(rs11 * h11);
            ug01 = at0 * sigm((top ? u12 : gu1[0]) + bgu1);
            ug11 = at1 * sigm((top ? u13 : gu1[1]) + bgu1);
        }
        lds_barrier();   // SYNC B: rh ready (x(t+2) prefetch stays in flight)

        // ---- cand GEMM: [x | r*h] @ Wc, 4 independent depth-4 chains ----
        f32x4 q0 = {0.f,0.f,0.f,0.f}, q1 = {0.f,0.f,0.f,0.f};
        f32x4 q2 = {0.f,0.f,0.f,0.f}, q3 = {0.f,0.f,0.f,0.f};
        {
            const bf16x8 afr0 = *(const bf16x8*)&rh[l16 * SB + 0 * 32 + quad * 8];
            const bf16x8 afr1 = *(const bf16x8*)&rh[l16 * SB + 1 * 32 + quad * 8];
            const bf16x8 afr2 = *(const bf16x8*)&rh[l16 * SB + 2 * 32 + quad * 8];
            const bf16x8 afr3 = *(const bf16x8*)&rh[l16 * SB + 3 * 32 + quad * 8];
            q0 = MFMA(afx[0], bcf[0][0], q0); q2 = MFMA(afx[0], bcf[1][0], q2);
            q1 = MFMA(afx[1], bcf[0][1], q1); q3 = MFMA(afx[1], bcf[1][1], q3);
            q0 = MFMA(afx[2], bcf[0][2], q0); q2 = MFMA(afx[2], bcf[1][2], q2);
            q1 = MFMA(afx[3], bcf[0][3], q1); q3 = MFMA(afx[3], bcf[1][3], q3);
            q0 = MFMA(afr0, bcf[0][4], q0);   q2 = MFMA(afr0, bcf[1][4], q2);
            q1 = MFMA(afr1, bcf[0][5], q1);   q3 = MFMA(afr1, bcf[1][5], q3);
            q0 = MFMA(afr2, bcf[0][6], q0);   q2 = MFMA(afr2, bcf[1][6], q2);
            q1 = MFMA(afr3, bcf[0][7], q1);   q3 = MFMA(afr3, bcf[1][7], q3);
        }
        const f32x4 cc0 = q0 + q1;   // col c0
        const f32x4 cc1 = q2 + q3;   // col c1
        const float c02 = __shfl_xor(cc0[2], 32, 64), c03 = __shfl_xor(cc0[3], 32, 64);
        const float c12 = __shfl_xor(cc1[2], 32, 64), c13 = __shfl_xor(cc1[3], 32, 64);

        // ---- update epilogue (full-lane, register h/u; OUT guarded to real rows) ----
        {
            const bool v0 = t < sl0;   // row r0 valid (pad rows: sl=0 -> always false)
            const bool v1 = t < sl1;   // row r0+1 valid
            // (row r0, col c0)
            {
                const float xv = (top ? c02 : cc0[0]) + bc0v;
                const float e  = __expf(2.0f * xv);
                const float cd = 1.0f - 2.0f * __builtin_amdgcn_rcpf(e + 1.0f);
                const float nh = fmaf(ug00, cd - h00, h00);
                h00 = v0 ? nh : h00;
                hb[r0 * SB + c0] = f2bf(h00);
                if (realr) OUT[((long)(b0 + r0) * TT + t) * HH + c0] = v0 ? nh : 0.f;
            }
            // (row r0+1, col c0)
            {
                const float xv = (top ? c03 : cc0[1]) + bc0v;
                const float e  = __expf(2.0f * xv);
                const float cd = 1.0f - 2.0f * __builtin_amdgcn_rcpf(e + 1.0f);
                const float nh = fmaf(ug10, cd - h10, h10);
                h10 = v1 ? nh : h10;
                hb[(r0 + 1) * SB + c0] = f2bf(h10);
                if (realr) OUT[((long)(b0 + r0 + 1) * TT + t) * HH + c0] = v1 ? nh : 0.f;
            }
            // (row r0, col c1)
            {
                const float xv = (top ? c12 : cc1[0]) + bc1v;
                const float e  = __expf(2.0f * xv);
                const float cd = 1.0f - 2.0f * __builtin_amdgcn_rcpf(e + 1.0f);
                const float nh = fmaf(ug01, cd - h01, h01);
                h01 = v0 ? nh : h01;
                hb[r0 * SB + c1] = f2bf(h01);
                if (realr) OUT[((long)(b0 + r0) * TT + t) * HH + c1] = v0 ? nh : 0.f;
            }
            // (row r0+1, col c1)
            {
                const float xv = (top ? c13 : cc1[1]) + bc1v;
                const float e  = __expf(2.0f * xv);
                const float cd = 1.0f - 2.0f * __builtin_amdgcn_rcpf(e + 1.0f);
                const float nh = fmaf(ug11, cd - h11, h11);
                h11 = v1 ? nh : h11;
                hb[(r0 + 1) * SB + c1] = f2bf(h11);
                if (realr) OUT[((long)(b0 + r0 + 1) * TT + t) * HH + c1] = v1 ? nh : 0.f;
            }
        }
        lds_barrier();   // SYNC A for t+1: h (and staged x) ready
    }

    // tail: outputs for t in [tmax, TT) are zeros (real rows only)
    const int n4 = (TT - tmax) * (HH / 4);
    for (int r = 0; r < BM; ++r) {
        float4* p = (float4*)(OUT + ((long)(b0 + r) * TT + tmax) * HH);
        for (int i = tid; i < n4; i += NTH) p[i] = make_float4(0.f, 0.f, 0.f, 0.f);
    }
}

extern "C" void kernel_launch(void* const* d_in, const int* in_sizes, int n_in,
                              void* d_out, int out_size, void* d_ws, size_t ws_size,
                              hipStream_t stream) {
    (void)in_sizes; (void)n_in; (void)d_ws; (void)ws_size; (void)out_size;
    const float* X   = (const float*)d_in[0];
    const float* ATT = (const float*)d_in[1];
    const int*   SL  = (const int*)d_in[2];
    const float* WG  = (const float*)d_in[3];
    const float* BG  = (const float*)d_in[4];
    const float* WC  = (const float*)d_in[5];
    const float* BC  = (const float*)d_in[6];
    float*       OUT = (float*)d_out;
    hipLaunchKernelGGL(augru_kernel, dim3(BB / BM), dim3(NTH), 0, stream,
                       X, ATT, SL, WG, BG, WC, BC, OUT);
}

// Round 15
// 737.844 us; speedup vs baseline: 1.4762x; 1.4762x over previous
//
#include <hip/hip_runtime.h>
#include <hip/hip_bf16.h>

// AUGRU (DIEN) fused recurrent kernel. fp32 I/O, bf16 MFMA compute.
// B=2048, T=200, D=H=128. Round 18: BM=4 TLP retry with the register cap
// removed. R17's __launch_bounds__(256,2) capped VGPR at 128 -> the 192-VGPR
// weight fragments spilled to scratch (VGPR 216->128, WRITE +148MB, 3x slow).
// Fix: __launch_bounds__(256,1). At VGPR~216 the HW already permits
// 2 waves/SIMD (halving threshold ~256), so two 4-wave blocks co-reside per
// CU naturally. Everything else identical to R17 (which PASSED correctness:
// pad rows 4..7 have sl=0 -> h frozen at 0 -> hb/rh zero-padded; OUT guarded).

#define BB   2048
#define TT   200
#define DD   128
#define HH   128
#define NG   256
#define BM   4       // batch rows per block (rows 4..15 of tiles = zero pad)
#define SB   136     // bf16 tile row stride (shorts): 68 dwords = 4 mod 32
#define NTH  256

typedef __attribute__((ext_vector_type(8))) __bf16 bf16x8;
typedef __attribute__((ext_vector_type(4))) float  f32x4;

#define MFMA(a, b, c) __builtin_amdgcn_mfma_f32_16x16x32_bf16((a), (b), (c), 0, 0, 0)

union bfu { __bf16 b; unsigned short u; };
__device__ __forceinline__ unsigned short f2bf(float f) { bfu c; c.b = (__bf16)f; return c.u; }
__device__ __forceinline__ __bf16 f2bfv(float f) { return (__bf16)f; }
__device__ __forceinline__ float sigm(float x) { return __builtin_amdgcn_rcpf(1.0f + __expf(-x)); }

// Barrier with LDS-ordering only (no vmcnt drain; x-prefetch + OUT stores
// stay in flight across steps). Cross-wave ordering here is LDS-only.
__device__ __forceinline__ void lds_barrier() {
    __builtin_amdgcn_sched_barrier(0);
    asm volatile("s_waitcnt lgkmcnt(0)" ::: "memory");
    __builtin_amdgcn_s_barrier();
    __builtin_amdgcn_sched_barrier(0);
}

__global__ __launch_bounds__(NTH, 1)
void augru_kernel(const float* __restrict__ X,    // [B,T,D]
                  const float* __restrict__ ATT,  // [B,T]
                  const int*   __restrict__ SL,   // [B]
                  const float* __restrict__ WG,   // [256,256]
                  const float* __restrict__ BG,   // [256]
                  const float* __restrict__ WC,   // [256,128]
                  const float* __restrict__ BC,   // [128]
                  float*       __restrict__ OUT)  // [B,T,H]
{
    __shared__ unsigned short xb[2][16 * SB];  // x_t double buffer, bf16, rows BM..15 = 0
    __shared__ unsigned short hb[16 * SB];     // h bf16 (A-frag source), rows BM..15 = 0
    __shared__ unsigned short rh[16 * SB];     // r*h bf16, rows BM..15 = 0
    __shared__ float attall[BM * TT];
    __shared__ int   slbuf[8];                 // rows >= BM: 0 (pad)

    const int tid  = threadIdx.x;
    const int wave = tid >> 6;       // 0..3
    const int lane = tid & 63;
    const int quad = lane >> 4;
    const int l16  = lane & 15;
    const int b0   = blockIdx.x * BM;
    const int qq   = quad & 1;       // row-group select after redistribution
    const int top  = quad >> 1;
    const int r0   = 4 * qq + 2 * top;   // this lane handles rows r0, r0+1 (may be pad)
    const bool realr = (r0 < BM);        // rows r0, r0+1 are real batch rows

    // ---------------- one-time init ----------------
    for (int i = tid; i < 2 * 16 * SB; i += NTH) xb[0][i] = 0;   // both buffers
    for (int i = tid; i < 16 * SB; i += NTH) hb[i] = 0;
    for (int i = tid; i < 16 * SB; i += NTH) rh[i] = 0;
    for (int i = tid; i < BM * TT; i += NTH) attall[i] = ATT[(long)b0 * TT + i];
    if (tid < 8) slbuf[tid] = (tid < BM) ? SL[b0 + tid] : 0;

    // Columns this thread owns (cand / r-gate / h / out): c0, c1 = c0+16.
    // u-gate cols: c0+128, c1+128.
    const int c0 = wave * 32 + l16;
    const int c1 = c0 + 16;
    const float bgr0 = BG[c0],      bgr1 = BG[c1];        // r-gate biases
    const float bgu0 = BG[c0 + HH], bgu1 = BG[c1 + HH];   // u-gate biases
    const float bc0v = BC[c0],      bc1v = BC[c1];        // cand biases

    // Weight B-fragments (bf16) in registers.
    // B-frag (16x16x32): lane holds B[k = kk*32 + quad*8 + j][col]
    bf16x8 bgf[4][8], bcf[2][8];
    {
        #pragma unroll
        for (int kk = 0; kk < 8; ++kk) {
            bf16x8 t0, t1, t2, t3, t4, t5;
            #pragma unroll
            for (int j = 0; j < 8; ++j) {
                const int k = kk * 32 + quad * 8 + j;
                t0[j] = f2bfv(WG[k * NG + c0]);
                t1[j] = f2bfv(WG[k * NG + c1]);
                t2[j] = f2bfv(WG[k * NG + c0 + HH]);
                t3[j] = f2bfv(WG[k * NG + c1 + HH]);
                t4[j] = f2bfv(WC[k * HH + c0]);
                t5[j] = f2bfv(WC[k * HH + c1]);
            }
            bgf[0][kk] = t0; bgf[1][kk] = t1; bgf[2][kk] = t2; bgf[3][kk] = t3;
            bcf[0][kk] = t4; bcf[1][kk] = t5;
        }
    }
    __syncthreads();   // full barrier once (init loads must land)

    int tmax = 0;
    #pragma unroll
    for (int r = 0; r < 8; ++r) tmax = max(tmax, slbuf[r]);
    const int sl0 = slbuf[r0], sl1 = slbuf[r0 + 1];   // pad rows: 0 -> never valid

    // Persistent per-thread state: h (fp32) for (rows r0,r0+1) x (cols c0,c1).
    float h00 = 0.f, h01 = 0.f, h10 = 0.f, h11 = 0.f;   // hXY: X=row, Y=col

    const int srow = tid >> 5;   // 0..7 (rows >= BM: no staging, xb pad rows stay 0)
    const int sseg = tid & 31;
    const bool stg = (srow < BM);

    // prologue: stage x(0), prefetch x(1)
    float4 xpre;
    if (stg && tmax > 0) {
        xpre = *(const float4*)&X[((long)(b0 + srow) * TT + 0) * DD + sseg * 4];
        ushort4 v; v.x = f2bf(xpre.x); v.y = f2bf(xpre.y); v.z = f2bf(xpre.z); v.w = f2bf(xpre.w);
        *(ushort4*)&xb[0][srow * SB + sseg * 4] = v;
        if (tmax > 1)
            xpre = *(const float4*)&X[((long)(b0 + srow) * TT + 1) * DD + sseg * 4];
    }
    lds_barrier();   // SYNC A for t=0 (x(1) prefetch stays in flight)

    // ---------------- time loop ----------------
    for (int t = 0; t < tmax; ++t) {
        const unsigned short* xc = &xb[t & 1][0];

        // x A-fragments: loaded once, reused by both GEMMs this step.
        bf16x8 afx[4];
        #pragma unroll
        for (int kk = 0; kk < 4; ++kk)
            afx[kk] = *(const bf16x8*)&xc[l16 * SB + kk * 32 + quad * 8];

        // attention scores for this step (pad rows: value irrelevant, h frozen)
        const float at0 = realr ? attall[r0 * TT + t] : 0.f;
        const float at1 = realr ? attall[(r0 + 1) * TT + t] : 0.f;

        // ---- gate GEMM: [x|h] @ Wg, 8 independent MFMA chains ----
        f32x4 a0 = {0.f,0.f,0.f,0.f}, a1 = {0.f,0.f,0.f,0.f};
        f32x4 a2 = {0.f,0.f,0.f,0.f}, a3 = {0.f,0.f,0.f,0.f};
        f32x4 a4 = {0.f,0.f,0.f,0.f}, a5 = {0.f,0.f,0.f,0.f};
        f32x4 a6 = {0.f,0.f,0.f,0.f}, a7 = {0.f,0.f,0.f,0.f};
        // x part (kk = 0..3)
        a0 = MFMA(afx[0], bgf[0][0], a0); a2 = MFMA(afx[0], bgf[1][0], a2);
        a4 = MFMA(afx[0], bgf[2][0], a4); a6 = MFMA(afx[0], bgf[3][0], a6);
        a1 = MFMA(afx[1], bgf[0][1], a1); a3 = MFMA(afx[1], bgf[1][1], a3);
        a5 = MFMA(afx[1], bgf[2][1], a5); a7 = MFMA(afx[1], bgf[3][1], a7);
        a0 = MFMA(afx[2], bgf[0][2], a0); a2 = MFMA(afx[2], bgf[1][2], a2);
        a4 = MFMA(afx[2], bgf[2][2], a4); a6 = MFMA(afx[2], bgf[3][2], a6);
        a1 = MFMA(afx[3], bgf[0][3], a1); a3 = MFMA(afx[3], bgf[1][3], a3);
        a5 = MFMA(afx[3], bgf[2][3], a5); a7 = MFMA(afx[3], bgf[3][3], a7);
        // h part (kk = 4..7)
        {
            const bf16x8 afh0 = *(const bf16x8*)&hb[l16 * SB + 0 * 32 + quad * 8];
            const bf16x8 afh1 = *(const bf16x8*)&hb[l16 * SB + 1 * 32 + quad * 8];
            const bf16x8 afh2 = *(const bf16x8*)&hb[l16 * SB + 2 * 32 + quad * 8];
            const bf16x8 afh3 = *(const bf16x8*)&hb[l16 * SB + 3 * 32 + quad * 8];
            a0 = MFMA(afh0, bgf[0][4], a0); a2 = MFMA(afh0, bgf[1][4], a2);
            a4 = MFMA(afh0, bgf[2][4], a4); a6 = MFMA(afh0, bgf[3][4], a6);
            a1 = MFMA(afh1, bgf[0][5], a1); a3 = MFMA(afh1, bgf[1][5], a3);
            a5 = MFMA(afh1, bgf[2][5], a5); a7 = MFMA(afh1, bgf[3][5], a7);
            a0 = MFMA(afh2, bgf[0][6], a0); a2 = MFMA(afh2, bgf[1][6], a2);
            a4 = MFMA(afh2, bgf[2][6], a4); a6 = MFMA(afh2, bgf[3][6], a6);
            a1 = MFMA(afh3, bgf[0][7], a1); a3 = MFMA(afh3, bgf[1][7], a3);
            a5 = MFMA(afh3, bgf[2][7], a5); a7 = MFMA(afh3, bgf[3][7], a7);
        }

        // stage x(t+1) into the other buffer; then prefetch x(t+2)
        if (stg && t + 1 < tmax) {
            ushort4 v; v.x = f2bf(xpre.x); v.y = f2bf(xpre.y); v.z = f2bf(xpre.z); v.w = f2bf(xpre.w);
            *(ushort4*)&xb[(t + 1) & 1][srow * SB + sseg * 4] = v;
            if (t + 2 < tmax)
                xpre = *(const float4*)&X[((long)(b0 + srow) * TT + (t + 2)) * DD + sseg * 4];
        }

        // ---- gate epilogue (full-lane via xor-32 redistribution) ----
        const f32x4 gr0 = a0 + a1;   // r-gate, col c0
        const f32x4 gr1 = a2 + a3;   // r-gate, col c1
        const f32x4 gu0 = a4 + a5;   // u-gate, col c0+128
        const f32x4 gu1 = a6 + a7;   // u-gate, col c1+128
        const float r02 = __shfl_xor(gr0[2], 32, 64), r03 = __shfl_xor(gr0[3], 32, 64);
        const float r12 = __shfl_xor(gr1[2], 32, 64), r13 = __shfl_xor(gr1[3], 32, 64);
        const float u02 = __shfl_xor(gu0[2], 32, 64), u03 = __shfl_xor(gu0[3], 32, 64);
        const float u12 = __shfl_xor(gu1[2], 32, 64), u13 = __shfl_xor(gu1[3], 32, 64);
        float ug00, ug01, ug10, ug11;   // att * sigmoid(u), [row][col]
        {
            // col c0
            const float rs00 = sigm((top ? r02 : gr0[0]) + bgr0);   // row r0
            const float rs10 = sigm((top ? r03 : gr0[1]) + bgr0);   // row r0+1
            rh[r0 * SB + c0]       = f2bf(rs00 * h00);
            rh[(r0 + 1) * SB + c0] = f2bf(rs10 * h10);
            ug00 = at0 * sigm((top ? u02 : gu0[0]) + bgu0);
            ug10 = at1 * sigm((top ? u03 : gu0[1]) + bgu0);
            // col c1
            const float rs01 = sigm((top ? r12 : gr1[0]) + bgr1);
            const float rs11 = sigm((top ? r13 : gr1[1]) + bgr1);
            rh[r0 * SB + c1]       = f2bf(rs01 * h01);
            rh[(r0 + 1) * SB + c1] = f2bf(rs11 * h11);
            ug01 = at0 * sigm((top ? u12 : gu1[0]) + bgu1);
            ug11 = at1 * sigm((top ? u13 : gu1[1]) + bgu1);
        }
        lds_barrier();   // SYNC B: rh ready (x(t+2) prefetch stays in flight)

        // ---- cand GEMM: [x | r*h] @ Wc, 4 independent depth-4 chains ----
        f32x4 q0 = {0.f,0.f,0.f,0.f}, q1 = {0.f,0.f,0.f,0.f};
        f32x4 q2 = {0.f,0.f,0.f,0.f}, q3 = {0.f,0.f,0.f,0.f};
        {
            const bf16x8 afr0 = *(const bf16x8*)&rh[l16 * SB + 0 * 32 + quad * 8];
            const bf16x8 afr1 = *(const bf16x8*)&rh[l16 * SB + 1 * 32 + quad * 8];
            const bf16x8 afr2 = *(const bf16x8*)&rh[l16 * SB + 2 * 32 + quad * 8];
            const bf16x8 afr3 = *(const bf16x8*)&rh[l16 * SB + 3 * 32 + quad * 8];
            q0 = MFMA(afx[0], bcf[0][0], q0); q2 = MFMA(afx[0], bcf[1][0], q2);
            q1 = MFMA(afx[1], bcf[0][1], q1); q3 = MFMA(afx[1], bcf[1][1], q3);
            q0 = MFMA(afx[2], bcf[0][2], q0); q2 = MFMA(afx[2], bcf[1][2], q2);
            q1 = MFMA(afx[3], bcf[0][3], q1); q3 = MFMA(afx[3], bcf[1][3], q3);
            q0 = MFMA(afr0, bcf[0][4], q0);   q2 = MFMA(afr0, bcf[1][4], q2);
            q1 = MFMA(afr1, bcf[0][5], q1);   q3 = MFMA(afr1, bcf[1][5], q3);
            q0 = MFMA(afr2, bcf[0][6], q0);   q2 = MFMA(afr2, bcf[1][6], q2);
            q1 = MFMA(afr3, bcf[0][7], q1);   q3 = MFMA(afr3, bcf[1][7], q3);
        }
        const f32x4 cc0 = q0 + q1;   // col c0
        const f32x4 cc1 = q2 + q3;   // col c1
        const float c02 = __shfl_xor(cc0[2], 32, 64), c03 = __shfl_xor(cc0[3], 32, 64);
        const float c12 = __shfl_xor(cc1[2], 32, 64), c13 = __shfl_xor(cc1[3], 32, 64);

        // ---- update epilogue (full-lane, register h/u; OUT guarded to real rows) ----
        {
            const bool v0 = t < sl0;   // row r0 valid (pad rows: sl=0 -> always false)
            const bool v1 = t < sl1;   // row r0+1 valid
            // (row r0, col c0)
            {
                const float xv = (top ? c02 : cc0[0]) + bc0v;
                const float e  = __expf(2.0f * xv);
                const float cd = 1.0f - 2.0f * __builtin_amdgcn_rcpf(e + 1.0f);
                const float nh = fmaf(ug00, cd - h00, h00);
                h00 = v0 ? nh : h00;
                hb[r0 * SB + c0] = f2bf(h00);
                if (realr) OUT[((long)(b0 + r0) * TT + t) * HH + c0] = v0 ? nh : 0.f;
            }
            // (row r0+1, col c0)
            {
                const float xv = (top ? c03 : cc0[1]) + bc0v;
                const float e  = __expf(2.0f * xv);
                const float cd = 1.0f - 2.0f * __builtin_amdgcn_rcpf(e + 1.0f);
                const float nh = fmaf(ug10, cd - h10, h10);
                h10 = v1 ? nh : h10;
                hb[(r0 + 1) * SB + c0] = f2bf(h10);
                if (realr) OUT[((long)(b0 + r0 + 1) * TT + t) * HH + c0] = v1 ? nh : 0.f;
            }
            // (row r0, col c1)
            {
                const float xv = (top ? c12 : cc1[0]) + bc1v;
                const float e  = __expf(2.0f * xv);
                const float cd = 1.0f - 2.0f * __builtin_amdgcn_rcpf(e + 1.0f);
                const float nh = fmaf(ug01, cd - h01, h01);
                h01 = v0 ? nh : h01;
                hb[r0 * SB + c1] = f2bf(h01);
                if (realr) OUT[((long)(b0 + r0) * TT + t) * HH + c1] = v0 ? nh : 0.f;
            }
            // (row r0+1, col c1)
            {
                const float xv = (top ? c13 : cc1[1]) + bc1v;
                const float e  = __expf(2.0f * xv);
                const float cd = 1.0f - 2.0f * __builtin_amdgcn_rcpf(e + 1.0f);
                const float nh = fmaf(ug11, cd - h11, h11);
                h11 = v1 ? nh : h11;
                hb[(r0 + 1) * SB + c1] = f2bf(h11);
                if (realr) OUT[((long)(b0 + r0 + 1) * TT + t) * HH + c1] = v1 ? nh : 0.f;
            }
        }
        lds_barrier();   // SYNC A for t+1: h (and staged x) ready
    }

    // tail: outputs for t in [tmax, TT) are zeros (real rows only)
    const int n4 = (TT - tmax) * (HH / 4);
    for (int r = 0; r < BM; ++r) {
        float4* p = (float4*)(OUT + ((long)(b0 + r) * TT + tmax) * HH);
        for (int i = tid; i < n4; i += NTH) p[i] = make_float4(0.f, 0.f, 0.f, 0.f);
    }
}

extern "C" void kernel_launch(void* const* d_in, const int* in_sizes, int n_in,
                              void* d_out, int out_size, void* d_ws, size_t ws_size,
                              hipStream_t stream) {
    (void)in_sizes; (void)n_in; (void)d_ws; (void)ws_size; (void)out_size;
    const float* X   = (const float*)d_in[0];
    const float* ATT = (const float*)d_in[1];
    const int*   SL  = (const int*)d_in[2];
    const float* WG  = (const float*)d_in[3];
    const float* BG  = (const float*)d_in[4];
    const float* WC  = (const float*)d_in[5];
    const float* BC  = (const float*)d_in[6];
    float*       OUT = (float*)d_out;
    hipLaunchKernelGGL(augru_kernel, dim3(BB / BM), dim3(NTH), 0, stream,
                       X, ATT, SL, WG, BG, WC, BC, OUT);
}

// Round 16
// 737.021 us; speedup vs baseline: 1.4779x; 1.0011x over previous
//
#include <hip/hip_runtime.h>
#include <hip/hip_bf16.h>

// AUGRU (DIEN) fused recurrent kernel. fp32 I/O, bf16 MFMA compute.
// B=2048, T=200, D=H=128. Round 19: BM=4 TLP, VGPR-trimmed for co-residency.
// R18 showed 2 blocks/CU never co-resided (Occupancy 9.7% = R8's; dur = 2x
// per-block): arch 212 + ~40 AGPR > 256/wave -> 1 wave/SIMD. This round
// shaves ~32 arch VGPRs with two local trims (no mapping/sync changes):
//  - gate accumulators 8 -> 4 (depth-8 chains, one per ntile; gr=a0+a1 adds gone)
//  - afx not cached across gate->cand; cand re-reads from xb[t&1] (valid all step)
// Target: total <= ~220 -> 2 waves/SIMD -> two independent 4-wave blocks/CU,
// each block's barrier/latency stalls hiding under the other's compute.

#define BB   2048
#define TT   200
#define DD   128
#define HH   128
#define NG   256
#define BM   4       // batch rows per block (rows 4..15 of tiles = zero pad)
#define SB   136     // bf16 tile row stride (shorts): 68 dwords = 4 mod 32
#define NTH  256

typedef __attribute__((ext_vector_type(8))) __bf16 bf16x8;
typedef __attribute__((ext_vector_type(4))) float  f32x4;

#define MFMA(a, b, c) __builtin_amdgcn_mfma_f32_16x16x32_bf16((a), (b), (c), 0, 0, 0)

union bfu { __bf16 b; unsigned short u; };
__device__ __forceinline__ unsigned short f2bf(float f) { bfu c; c.b = (__bf16)f; return c.u; }
__device__ __forceinline__ __bf16 f2bfv(float f) { return (__bf16)f; }
__device__ __forceinline__ float sigm(float x) { return __builtin_amdgcn_rcpf(1.0f + __expf(-x)); }

// Barrier with LDS-ordering only (no vmcnt drain; x-prefetch + OUT stores
// stay in flight across steps). Cross-wave ordering here is LDS-only.
__device__ __forceinline__ void lds_barrier() {
    __builtin_amdgcn_sched_barrier(0);
    asm volatile("s_waitcnt lgkmcnt(0)" ::: "memory");
    __builtin_amdgcn_s_barrier();
    __builtin_amdgcn_sched_barrier(0);
}

__global__ __launch_bounds__(NTH, 1)
void augru_kernel(const float* __restrict__ X,    // [B,T,D]
                  const float* __restrict__ ATT,  // [B,T]
                  const int*   __restrict__ SL,   // [B]
                  const float* __restrict__ WG,   // [256,256]
                  const float* __restrict__ BG,   // [256]
                  const float* __restrict__ WC,   // [256,128]
                  const float* __restrict__ BC,   // [128]
                  float*       __restrict__ OUT)  // [B,T,H]
{
    __shared__ unsigned short xb[2][16 * SB];  // x_t double buffer, bf16, rows BM..15 = 0
    __shared__ unsigned short hb[16 * SB];     // h bf16 (A-frag source), rows BM..15 = 0
    __shared__ unsigned short rh[16 * SB];     // r*h bf16, rows BM..15 = 0
    __shared__ float attall[BM * TT];
    __shared__ int   slbuf[8];                 // rows >= BM: 0 (pad)

    const int tid  = threadIdx.x;
    const int wave = tid >> 6;       // 0..3
    const int lane = tid & 63;
    const int quad = lane >> 4;
    const int l16  = lane & 15;
    const int b0   = blockIdx.x * BM;
    const int qq   = quad & 1;       // row-group select after redistribution
    const int top  = quad >> 1;
    const int r0   = 4 * qq + 2 * top;   // this lane handles rows r0, r0+1 (may be pad)
    const bool realr = (r0 < BM);        // rows r0, r0+1 are real batch rows

    // ---------------- one-time init ----------------
    for (int i = tid; i < 2 * 16 * SB; i += NTH) xb[0][i] = 0;   // both buffers
    for (int i = tid; i < 16 * SB; i += NTH) hb[i] = 0;
    for (int i = tid; i < 16 * SB; i += NTH) rh[i] = 0;
    for (int i = tid; i < BM * TT; i += NTH) attall[i] = ATT[(long)b0 * TT + i];
    if (tid < 8) slbuf[tid] = (tid < BM) ? SL[b0 + tid] : 0;

    // Columns this thread owns (cand / r-gate / h / out): c0, c1 = c0+16.
    // u-gate cols: c0+128, c1+128.
    const int c0 = wave * 32 + l16;
    const int c1 = c0 + 16;
    const float bgr0 = BG[c0],      bgr1 = BG[c1];        // r-gate biases
    const float bgu0 = BG[c0 + HH], bgu1 = BG[c1 + HH];   // u-gate biases
    const float bc0v = BC[c0],      bc1v = BC[c1];        // cand biases

    // Weight B-fragments (bf16) in registers.
    // B-frag (16x16x32): lane holds B[k = kk*32 + quad*8 + j][col]
    bf16x8 bgf[4][8], bcf[2][8];
    {
        #pragma unroll
        for (int kk = 0; kk < 8; ++kk) {
            bf16x8 t0, t1, t2, t3, t4, t5;
            #pragma unroll
            for (int j = 0; j < 8; ++j) {
                const int k = kk * 32 + quad * 8 + j;
                t0[j] = f2bfv(WG[k * NG + c0]);
                t1[j] = f2bfv(WG[k * NG + c1]);
                t2[j] = f2bfv(WG[k * NG + c0 + HH]);
                t3[j] = f2bfv(WG[k * NG + c1 + HH]);
                t4[j] = f2bfv(WC[k * HH + c0]);
                t5[j] = f2bfv(WC[k * HH + c1]);
            }
            bgf[0][kk] = t0; bgf[1][kk] = t1; bgf[2][kk] = t2; bgf[3][kk] = t3;
            bcf[0][kk] = t4; bcf[1][kk] = t5;
        }
    }
    __syncthreads();   // full barrier once (init loads must land)

    int tmax = 0;
    #pragma unroll
    for (int r = 0; r < 8; ++r) tmax = max(tmax, slbuf[r]);
    const int sl0 = slbuf[r0], sl1 = slbuf[r0 + 1];   // pad rows: 0 -> never valid

    // Persistent per-thread state: h (fp32) for (rows r0,r0+1) x (cols c0,c1).
    float h00 = 0.f, h01 = 0.f, h10 = 0.f, h11 = 0.f;   // hXY: X=row, Y=col

    const int srow = tid >> 5;   // 0..7 (rows >= BM: no staging, xb pad rows stay 0)
    const int sseg = tid & 31;
    const bool stg = (srow < BM);

    // prologue: stage x(0), prefetch x(1)
    float4 xpre;
    if (stg && tmax > 0) {
        xpre = *(const float4*)&X[((long)(b0 + srow) * TT + 0) * DD + sseg * 4];
        ushort4 v; v.x = f2bf(xpre.x); v.y = f2bf(xpre.y); v.z = f2bf(xpre.z); v.w = f2bf(xpre.w);
        *(ushort4*)&xb[0][srow * SB + sseg * 4] = v;
        if (tmax > 1)
            xpre = *(const float4*)&X[((long)(b0 + srow) * TT + 1) * DD + sseg * 4];
    }
    lds_barrier();   // SYNC A for t=0 (x(1) prefetch stays in flight)

    // ---------------- time loop ----------------
    for (int t = 0; t < tmax; ++t) {
        const unsigned short* xc = &xb[t & 1][0];

        // attention scores for this step (pad rows: value irrelevant, h frozen)
        const float at0 = realr ? attall[r0 * TT + t] : 0.f;
        const float at1 = realr ? attall[(r0 + 1) * TT + t] : 0.f;

        // ---- gate GEMM: [x|h] @ Wg, 4 depth-8 MFMA chains (one per ntile) ----
        // a0: (c0, r)  a1: (c1, r)  a2: (c0+128, u)  a3: (c1+128, u)
        f32x4 a0 = {0.f,0.f,0.f,0.f}, a1 = {0.f,0.f,0.f,0.f};
        f32x4 a2 = {0.f,0.f,0.f,0.f}, a3 = {0.f,0.f,0.f,0.f};
        {
            // x part (kk = 0..3) — fragments scoped: not live past this block
            const bf16x8 fx0 = *(const bf16x8*)&xc[l16 * SB + 0 * 32 + quad * 8];
            const bf16x8 fx1 = *(const bf16x8*)&xc[l16 * SB + 1 * 32 + quad * 8];
            const bf16x8 fx2 = *(const bf16x8*)&xc[l16 * SB + 2 * 32 + quad * 8];
            const bf16x8 fx3 = *(const bf16x8*)&xc[l16 * SB + 3 * 32 + quad * 8];
            a0 = MFMA(fx0, bgf[0][0], a0); a1 = MFMA(fx0, bgf[1][0], a1);
            a2 = MFMA(fx0, bgf[2][0], a2); a3 = MFMA(fx0, bgf[3][0], a3);
            a0 = MFMA(fx1, bgf[0][1], a0); a1 = MFMA(fx1, bgf[1][1], a1);
            a2 = MFMA(fx1, bgf[2][1], a2); a3 = MFMA(fx1, bgf[3][1], a3);
            a0 = MFMA(fx2, bgf[0][2], a0); a1 = MFMA(fx2, bgf[1][2], a1);
            a2 = MFMA(fx2, bgf[2][2], a2); a3 = MFMA(fx2, bgf[3][2], a3);
            a0 = MFMA(fx3, bgf[0][3], a0); a1 = MFMA(fx3, bgf[1][3], a1);
            a2 = MFMA(fx3, bgf[2][3], a2); a3 = MFMA(fx3, bgf[3][3], a3);
        }
        {
            // h part (kk = 4..7)
            const bf16x8 fh0 = *(const bf16x8*)&hb[l16 * SB + 0 * 32 + quad * 8];
            const bf16x8 fh1 = *(const bf16x8*)&hb[l16 * SB + 1 * 32 + quad * 8];
            const bf16x8 fh2 = *(const bf16x8*)&hb[l16 * SB + 2 * 32 + quad * 8];
            const bf16x8 fh3 = *(const bf16x8*)&hb[l16 * SB + 3 * 32 + quad * 8];
            a0 = MFMA(fh0, bgf[0][4], a0); a1 = MFMA(fh0, bgf[1][4], a1);
            a2 = MFMA(fh0, bgf[2][4], a2); a3 = MFMA(fh0, bgf[3][4], a3);
            a0 = MFMA(fh1, bgf[0][5], a0); a1 = MFMA(fh1, bgf[1][5], a1);
            a2 = MFMA(fh1, bgf[2][5], a2); a3 = MFMA(fh1, bgf[3][5], a3);
            a0 = MFMA(fh2, bgf[0][6], a0); a1 = MFMA(fh2, bgf[1][6], a1);
            a2 = MFMA(fh2, bgf[2][6], a2); a3 = MFMA(fh2, bgf[3][6], a3);
            a0 = MFMA(fh3, bgf[0][7], a0); a1 = MFMA(fh3, bgf[1][7], a1);
            a2 = MFMA(fh3, bgf[2][7], a2); a3 = MFMA(fh3, bgf[3][7], a3);
        }

        // stage x(t+1) into the other buffer; then prefetch x(t+2)
        if (stg && t + 1 < tmax) {
            ushort4 v; v.x = f2bf(xpre.x); v.y = f2bf(xpre.y); v.z = f2bf(xpre.z); v.w = f2bf(xpre.w);
            *(ushort4*)&xb[(t + 1) & 1][srow * SB + sseg * 4] = v;
            if (t + 2 < tmax)
                xpre = *(const float4*)&X[((long)(b0 + srow) * TT + (t + 2)) * DD + sseg * 4];
        }

        // ---- gate epilogue (full-lane via xor-32 redistribution) ----
        const float r02 = __shfl_xor(a0[2], 32, 64), r03 = __shfl_xor(a0[3], 32, 64);
        const float r12 = __shfl_xor(a1[2], 32, 64), r13 = __shfl_xor(a1[3], 32, 64);
        const float u02 = __shfl_xor(a2[2], 32, 64), u03 = __shfl_xor(a2[3], 32, 64);
        const float u12 = __shfl_xor(a3[2], 32, 64), u13 = __shfl_xor(a3[3], 32, 64);
        float ug00, ug01, ug10, ug11;   // att * sigmoid(u), [row][col]
        {
            // col c0
            const float rs00 = sigm((top ? r02 : a0[0]) + bgr0);   // row r0
            const float rs10 = sigm((top ? r03 : a0[1]) + bgr0);   // row r0+1
            rh[r0 * SB + c0]       = f2bf(rs00 * h00);
            rh[(r0 + 1) * SB + c0] = f2bf(rs10 * h10);
            ug00 = at0 * sigm((top ? u02 : a2[0]) + bgu0);
            ug10 = at1 * sigm((top ? u03 : a2[1]) + bgu0);
            // col c1
            const float rs01 = sigm((top ? r12 : a1[0]) + bgr1);
            const float rs11 = sigm((top ? r13 : a1[1]) + bgr1);
            rh[r0 * SB + c1]       = f2bf(rs01 * h01);
            rh[(r0 + 1) * SB + c1] = f2bf(rs11 * h11);
            ug01 = at0 * sigm((top ? u12 : a3[0]) + bgu1);
            ug11 = at1 * sigm((top ? u13 : a3[1]) + bgu1);
        }
        lds_barrier();   // SYNC B: rh ready (x(t+2) prefetch stays in flight)

        // ---- cand GEMM: [x | r*h] @ Wc, 4 depth-4 chains ----
        // x fragments re-read from xb[t&1] (still valid; staging wrote the
        // OTHER buffer). Saves 16 VGPRs vs caching across the barrier.
        f32x4 q0 = {0.f,0.f,0.f,0.f}, q1 = {0.f,0.f,0.f,0.f};
        f32x4 q2 = {0.f,0.f,0.f,0.f}, q3 = {0.f,0.f,0.f,0.f};
        {
            const bf16x8 gx0 = *(const bf16x8*)&xc[l16 * SB + 0 * 32 + quad * 8];
            const bf16x8 gx1 = *(const bf16x8*)&xc[l16 * SB + 1 * 32 + quad * 8];
            const bf16x8 gx2 = *(const bf16x8*)&xc[l16 * SB + 2 * 32 + quad * 8];
            const bf16x8 gx3 = *(const bf16x8*)&xc[l16 * SB + 3 * 32 + quad * 8];
            q0 = MFMA(gx0, bcf[0][0], q0); q2 = MFMA(gx0, bcf[1][0], q2);
            q1 = MFMA(gx1, bcf[0][1], q1); q3 = MFMA(gx1, bcf[1][1], q3);
            q0 = MFMA(gx2, bcf[0][2], q0); q2 = MFMA(gx2, bcf[1][2], q2);
            q1 = MFMA(gx3, bcf[0][3], q1); q3 = MFMA(gx3, bcf[1][3], q3);
        }
        {
            const bf16x8 fr0 = *(const bf16x8*)&rh[l16 * SB + 0 * 32 + quad * 8];
            const bf16x8 fr1 = *(const bf16x8*)&rh[l16 * SB + 1 * 32 + quad * 8];
            const bf16x8 fr2 = *(const bf16x8*)&rh[l16 * SB + 2 * 32 + quad * 8];
            const bf16x8 fr3 = *(const bf16x8*)&rh[l16 * SB + 3 * 32 + quad * 8];
            q0 = MFMA(fr0, bcf[0][4], q0);   q2 = MFMA(fr0, bcf[1][4], q2);
            q1 = MFMA(fr1, bcf[0][5], q1);   q3 = MFMA(fr1, bcf[1][5], q3);
            q0 = MFMA(fr2, bcf[0][6], q0);   q2 = MFMA(fr2, bcf[1][6], q2);
            q1 = MFMA(fr3, bcf[0][7], q1);   q3 = MFMA(fr3, bcf[1][7], q3);
        }
        const f32x4 cc0 = q0 + q1;   // col c0
        const f32x4 cc1 = q2 + q3;   // col c1
        const float c02 = __shfl_xor(cc0[2], 32, 64), c03 = __shfl_xor(cc0[3], 32, 64);
        const float c12 = __shfl_xor(cc1[2], 32, 64), c13 = __shfl_xor(cc1[3], 32, 64);

        // ---- update epilogue (full-lane, register h/u; OUT guarded to real rows) ----
        {
            const bool v0 = t < sl0;   // row r0 valid (pad rows: sl=0 -> always false)
            const bool v1 = t < sl1;   // row r0+1 valid
            // (row r0, col c0)
            {
                const float xv = (top ? c02 : cc0[0]) + bc0v;
                const float e  = __expf(2.0f * xv);
                const float cd = 1.0f - 2.0f * __builtin_amdgcn_rcpf(e + 1.0f);
                const float nh = fmaf(ug00, cd - h00, h00);
                h00 = v0 ? nh : h00;
                hb[r0 * SB + c0] = f2bf(h00);
                if (realr) OUT[((long)(b0 + r0) * TT + t) * HH + c0] = v0 ? nh : 0.f;
            }
            // (row r0+1, col c0)
            {
                const float xv = (top ? c03 : cc0[1]) + bc0v;
                const float e  = __expf(2.0f * xv);
                const float cd = 1.0f - 2.0f * __builtin_amdgcn_rcpf(e + 1.0f);
                const float nh = fmaf(ug10, cd - h10, h10);
                h10 = v1 ? nh : h10;
                hb[(r0 + 1) * SB + c0] = f2bf(h10);
                if (realr) OUT[((long)(b0 + r0 + 1) * TT + t) * HH + c0] = v1 ? nh : 0.f;
            }
            // (row r0, col c1)
            {
                const float xv = (top ? c12 : cc1[0]) + bc1v;
                const float e  = __expf(2.0f * xv);
                const float cd = 1.0f - 2.0f * __builtin_amdgcn_rcpf(e + 1.0f);
                const float nh = fmaf(ug01, cd - h01, h01);
                h01 = v0 ? nh : h01;
                hb[r0 * SB + c1] = f2bf(h01);
                if (realr) OUT[((long)(b0 + r0) * TT + t) * HH + c1] = v0 ? nh : 0.f;
            }
            // (row r0+1, col c1)
            {
                const float xv = (top ? c13 : cc1[1]) + bc1v;
                const float e  = __expf(2.0f * xv);
                const float cd = 1.0f - 2.0f * __builtin_amdgcn_rcpf(e + 1.0f);
                const float nh = fmaf(ug11, cd - h11, h11);
                h11 = v1 ? nh : h11;
                hb[(r0 + 1) * SB + c1] = f2bf(h11);
                if (realr) OUT[((long)(b0 + r0 + 1) * TT + t) * HH + c1] = v1 ? nh : 0.f;
            }
        }
        lds_barrier();   // SYNC A for t+1: h (and staged x) ready
    }

    // tail: outputs for t in [tmax, TT) are zeros (real rows only)
    const int n4 = (TT - tmax) * (HH / 4);
    for (int r = 0; r < BM; ++r) {
        float4* p = (float4*)(OUT + ((long)(b0 + r) * TT + tmax) * HH);
        for (int i = tid; i < n4; i += NTH) p[i] = make_float4(0.f, 0.f, 0.f, 0.f);
    }
}

extern "C" void kernel_launch(void* const* d_in, const int* in_sizes, int n_in,
                              void* d_out, int out_size, void* d_ws, size_t ws_size,
                              hipStream_t stream) {
    (void)in_sizes; (void)n_in; (void)d_ws; (void)ws_size; (void)out_size;
    const float* X   = (const float*)d_in[0];
    const float* ATT = (const float*)d_in[1];
    const int*   SL  = (const int*)d_in[2];
    const float* WG  = (const float*)d_in[3];
    const float* BG  = (const float*)d_in[4];
    const float* WC  = (const float*)d_in[5];
    const float* BC  = (const float*)d_in[6];
    float*       OUT = (float*)d_out;
    hipLaunchKernelGGL(augru_kernel, dim3(BB / BM), dim3(NTH), 0, stream,
                       X, ATT, SL, WG, BG, WC, BC, OUT);
}